// Round 5
// baseline (777.603 us; speedup 1.0000x reference)
//
#include <hip/hip_runtime.h>
#include <stdint.h>

#define N_TOK 8192
#define EMB 1024
#define HID 4096
#define NEXP 8

// ---- types ----
typedef _Float16 f16x8 __attribute__((ext_vector_type(8)));
typedef _Float16 f16x4 __attribute__((ext_vector_type(4)));
typedef short    s16x8 __attribute__((ext_vector_type(8)));
typedef unsigned short u16x8 __attribute__((ext_vector_type(8)));
typedef float    f32x4 __attribute__((ext_vector_type(4)));

typedef __attribute__((address_space(1))) const void gvoid_t;
typedef __attribute__((address_space(3))) void lvoid_t;

__device__ __forceinline__ void async16(const void* g, void* l) {
  __builtin_amdgcn_global_load_lds((gvoid_t*)g, (lvoid_t*)l, 16, 0, 0);
}

__device__ __forceinline__ unsigned short f2bf(float f) {
  unsigned u = __builtin_bit_cast(unsigned, f);
  u += 0x7fffu + ((u >> 16) & 1u);   // RTNE (no NaN in this data)
  return (unsigned short)(u >> 16);
}

// ---- cast x -> bf16 (FFN A operand) + fp16 hi/lo split (router A operand) ----
__global__ __launch_bounds__(256) void k_cast_x(const float* __restrict__ x,
    unsigned short* __restrict__ xb, _Float16* __restrict__ xhi, _Float16* __restrict__ xlo) {
  int i = (blockIdx.x * 256 + threadIdx.x) << 2;
  float4 v = *(const float4*)(x + i);
  ushort4 b;
  b.x = f2bf(v.x); b.y = f2bf(v.y); b.z = f2bf(v.z); b.w = f2bf(v.w);
  *(ushort4*)(xb + i) = b;
  float vv[4] = {v.x, v.y, v.z, v.w};
  f16x4 hi, lo;
#pragma unroll
  for (int j = 0; j < 4; j++) {
    _Float16 h = (_Float16)vv[j];
    hi[j] = h;
    lo[j] = (_Float16)(vv[j] - (float)h);
  }
  *(f16x4*)(xhi + i) = hi;
  *(f16x4*)(xlo + i) = lo;
}

// ---- transpose+cast Wr1 [k][n] -> [n][k] fp16 hi/lo, scaled by 256 (argmax-invariant) ----
__global__ __launch_bounds__(256) void k_trans_wr1(const float* __restrict__ src,
    _Float16* __restrict__ dhi, _Float16* __restrict__ dlo) {
  int nblk = blockIdx.x >> 4, kc = blockIdx.x & 15;
  int n = (nblk << 8) + threadIdx.x;
  int k0 = kc << 6;
  for (int k = k0; k < k0 + 64; k += 8) {
    f16x8 hi, lo;
#pragma unroll
    for (int j = 0; j < 8; j++) {
      float w = src[(size_t)(k + j) * EMB + n] * 256.0f;
      _Float16 h = (_Float16)w;
      hi[j] = h;
      lo[j] = (_Float16)(w - (float)h);
    }
    *(f16x8*)(dhi + (size_t)n * EMB + k) = hi;
    *(f16x8*)(dlo + (size_t)n * EMB + k) = lo;
  }
}

// ---- LDS-tiled transpose+cast expert weights [e][K][Nn] fp32 -> [e][Nn][K] bf16 ----
__global__ __launch_bounds__(256) void k_transcast_v2(const float* __restrict__ src,
    unsigned short* __restrict__ dst, int K, int Nn, int ktiles, int ntiles) {
  __shared__ __align__(16) unsigned short lds[256 * 72];  // 36,864 B, row stride 72
  int b = blockIdx.x;
  int e = b / (ktiles * ntiles);
  int r = b % (ktiles * ntiles);
  int kt = r / ntiles, nt = r % ntiles;
  int k0 = kt << 6, n0 = nt << 8;
  const float* s = src + (size_t)e * K * Nn;
  unsigned short* d = dst + (size_t)e * K * Nn;
  int tid = threadIdx.x;
  const float* scol = s + n0 + tid;
#pragma unroll 4
  for (int k = 0; k < 64; k += 2) {
    float a  = scol[(size_t)(k0 + k) * Nn];
    float bv = scol[(size_t)(k0 + k + 1) * Nn];
    unsigned p = (unsigned)f2bf(a) | ((unsigned)f2bf(bv) << 16);
    *(unsigned*)(lds + tid * 72 + k) = p;
  }
  __syncthreads();
  int c = tid & 7, nl = tid >> 3;
#pragma unroll
  for (int p2 = 0; p2 < 8; p2++) {
    int n = (p2 << 5) + nl;
    u16x8 v = *(const u16x8*)(lds + n * 72 + (c << 3));
    *(u16x8*)(d + (size_t)(n0 + n) * K + k0 + (c << 3)) = v;
  }
}

// ---- router GEMM: h_s = relu(256*(x@Wr1+br1)) via fp16 2-way split, fp32-accurate ----
// (exact round-0 structure: best measured)
__global__ __launch_bounds__(256) void k_router_gemm(
    const _Float16* __restrict__ Ah, const _Float16* __restrict__ Al,
    const _Float16* __restrict__ Bh, const _Float16* __restrict__ Bl,
    const float* __restrict__ br1, float* __restrict__ hOut) {
  __shared__ __align__(16) _Float16 sAh[4096], sAl[4096], sBh[4096], sBl[4096];
  const int tid = threadIdx.x, lane = tid & 63, wave = tid >> 6;
  const int m0 = (blockIdx.x >> 3) << 7;
  const int n0 = (blockIdx.x & 7) << 7;
  const int srow = (wave << 5) + (lane >> 2);
  const int scol = (lane & 3) << 3;
  const size_t aBase = (size_t)(m0 + srow) * EMB + scol;
  const size_t bBase = (size_t)(n0 + srow) * EMB + scol;
  _Float16* lAh = sAh + (wave << 10);
  _Float16* lAl = sAl + (wave << 10);
  _Float16* lBh = sBh + (wave << 10);
  _Float16* lBl = sBl + (wave << 10);
  const int q = lane >> 4, c = lane & 15;
  const int msub = (wave & 1) << 6, nsub = (wave >> 1) << 6;
  f32x4 acc[4][4];
#pragma unroll
  for (int i = 0; i < 4; i++)
#pragma unroll
    for (int j = 0; j < 4; j++) acc[i][j] = (f32x4){0.f, 0.f, 0.f, 0.f};

  for (int kk = 0; kk < EMB; kk += 32) {
    async16(Ah + aBase + kk, lAh);
    async16(Ah + aBase + 16 * EMB + kk, lAh + 512);
    async16(Al + aBase + kk, lAl);
    async16(Al + aBase + 16 * EMB + kk, lAl + 512);
    async16(Bh + bBase + kk, lBh);
    async16(Bh + bBase + 16 * EMB + kk, lBh + 512);
    async16(Bl + bBase + kk, lBl);
    async16(Bl + bBase + 16 * EMB + kk, lBl + 512);
    __syncthreads();
    f16x8 fah[4], fal[4], fbh[4], fbl[4];
#pragma unroll
    for (int i = 0; i < 4; i++) {
      int ar = msub + (i << 4) + c;
      int br = nsub + (i << 4) + c;
      fah[i] = *(const f16x8*)(sAh + (ar << 5) + (q << 3));
      fal[i] = *(const f16x8*)(sAl + (ar << 5) + (q << 3));
      fbh[i] = *(const f16x8*)(sBh + (br << 5) + (q << 3));
      fbl[i] = *(const f16x8*)(sBl + (br << 5) + (q << 3));
    }
#pragma unroll
    for (int mi = 0; mi < 4; mi++)
#pragma unroll
      for (int ni = 0; ni < 4; ni++) {
        acc[mi][ni] = __builtin_amdgcn_mfma_f32_16x16x32_f16(fah[mi], fbh[ni], acc[mi][ni], 0, 0, 0);
        acc[mi][ni] = __builtin_amdgcn_mfma_f32_16x16x32_f16(fah[mi], fbl[ni], acc[mi][ni], 0, 0, 0);
        acc[mi][ni] = __builtin_amdgcn_mfma_f32_16x16x32_f16(fal[mi], fbh[ni], acc[mi][ni], 0, 0, 0);
      }
    __syncthreads();
  }
#pragma unroll
  for (int mi = 0; mi < 4; mi++)
#pragma unroll
    for (int ni = 0; ni < 4; ni++) {
      int gn = n0 + nsub + (ni << 4) + c;
      float bias = 256.0f * br1[gn];
#pragma unroll
      for (int i2 = 0; i2 < 4; i2++) {
        int gm = m0 + msub + (mi << 4) + (q << 2) + i2;
        float v = acc[mi][ni][i2] + bias;
        hOut[(size_t)gm * EMB + gn] = v > 0.f ? v : 0.f;
      }
    }
}

// ---- logits + argmax (first-max tie-break, matches np.argmax) ----
__global__ __launch_bounds__(256) void k_logits(const float* __restrict__ h,
    const float* __restrict__ Wr2, const float* __restrict__ br2, int* __restrict__ chosen) {
  __shared__ __align__(16) float sW[EMB * NEXP];
  int tid = threadIdx.x;
  for (int i = tid; i < EMB * NEXP; i += 256) sW[i] = Wr2[i];
  __syncthreads();
  int lane = tid & 63, wave = tid >> 6;
  int t = blockIdx.x * 4 + wave;
  const float* hr = h + (size_t)t * EMB;
  float acc[8] = {0.f, 0.f, 0.f, 0.f, 0.f, 0.f, 0.f, 0.f};
#pragma unroll
  for (int i = 0; i < 16; i++) {
    int k = (i << 6) + lane;
    float v = hr[k];
    float4 w0 = *(const float4*)(sW + (k << 3));
    float4 w1 = *(const float4*)(sW + (k << 3) + 4);
    acc[0] += v * w0.x; acc[1] += v * w0.y; acc[2] += v * w0.z; acc[3] += v * w0.w;
    acc[4] += v * w1.x; acc[5] += v * w1.y; acc[6] += v * w1.z; acc[7] += v * w1.w;
  }
#pragma unroll
  for (int off = 32; off > 0; off >>= 1)
#pragma unroll
    for (int e = 0; e < 8; e++) acc[e] += __shfl_down(acc[e], off);
  if (lane == 0) {
    float best = acc[0] + 256.0f * br2[0];
    int bi = 0;
#pragma unroll
    for (int e = 1; e < 8; e++) {
      float l = acc[e] + 256.0f * br2[e];
      if (l > best) { best = l; bi = e; }
    }
    chosen[t] = bi;
  }
}

// ---- tiny routing-bookkeeping kernels ----
// meta: [0..7] counts, [8..15] cursors, [16..24] offsets, [25] T128, [26] T256,
//       [32..103] sched128 e, [112..183] m0, [192..263] end,
//       [288..367] sched256 e, [368..447] m0, [448..527] end
__global__ void k_zero(int* meta) { meta[threadIdx.x] = 0; }

__global__ __launch_bounds__(256) void k_hist(const int* __restrict__ chosen, int* meta) {
  int i = blockIdx.x * 256 + threadIdx.x;
  atomicAdd(&meta[chosen[i]], 1);
}

__global__ __launch_bounds__(128) void k_sched(int* meta) {
  __shared__ int cnt[8];
  int tid = threadIdx.x;
  if (tid < 8) cnt[tid] = meta[tid];
  __syncthreads();
  int off[9]; off[0] = 0;
#pragma unroll
  for (int e = 0; e < 8; e++) off[e + 1] = off[e] + cnt[e];
  if (tid < 8) meta[16 + tid] = off[tid];
  // 128-row schedule (kept for compatibility; unused by FFN kernels now)
  int ts[9]; ts[0] = 0;
#pragma unroll
  for (int e = 0; e < 8; e++) ts[e + 1] = ts[e] + ((cnt[e] + 127) >> 7);
  int T = ts[8];
  if (tid == 0) { meta[24] = off[8]; meta[25] = T; }
  if (tid < T) {
    int e = 0;
    while (ts[e + 1] <= tid) e++;
    int m = off[e] + ((tid - ts[e]) << 7);
    int end = off[e + 1];
    meta[32 + tid] = e;
    meta[112 + tid] = m;
    meta[192 + tid] = (m + 128 < end) ? m + 128 : end;
  }
  // 256-row schedule (used by k_ffn1 / k_ffn2): T2 <= 40
  int ts2[9]; ts2[0] = 0;
#pragma unroll
  for (int e = 0; e < 8; e++) ts2[e + 1] = ts2[e] + ((cnt[e] + 255) >> 8);
  int T2 = ts2[8];
  if (tid == 0) meta[26] = T2;
  if (tid < T2) {
    int e = 0;
    while (ts2[e + 1] <= tid) e++;
    int m = off[e] + ((tid - ts2[e]) << 8);
    int end = off[e + 1];
    meta[288 + tid] = e;
    meta[368 + tid] = m;
    meta[448 + tid] = (m + 256 < end) ? m + 256 : end;
  }
}

__global__ __launch_bounds__(256) void k_scatter(const int* __restrict__ chosen,
                                                 int* meta, int* __restrict__ perm) {
  int i = blockIdx.x * 256 + threadIdx.x;
  int e = chosen[i];
  int pos = meta[16 + e] + atomicAdd(&meta[8 + e], 1);
  perm[pos] = i;
}

// ---- FFN layer 1: 256x128 tile, BK=64, 8 waves, 48 KB LDS, drain loop ----
// hidden = relu(x[perm] @ W1[e] + b1[e]).
// Chunked XCD swizzle (1280 = 8*160): each XCD owns a contiguous span of 160 wgs
// = 5 m-tiles x 32 n-tiles -> A-panel (2 MB) reused 32x from that XCD's L2.
__global__ __launch_bounds__(512) void k_ffn1(
    const unsigned short* __restrict__ xb, const unsigned short* __restrict__ w1t,
    const float* __restrict__ b1, const int* __restrict__ perm,
    const int* __restrict__ meta, unsigned short* __restrict__ hidden) {
  const int wg = (blockIdx.x & 7) * 160 + (blockIdx.x >> 3);  // XCD chunk swizzle
  const int mt = wg >> 5;
  if (mt >= meta[26]) return;
  const int nt = wg & 31;
  const int e = meta[288 + mt];
  const int row0 = meta[368 + mt];
  const int rend = meta[448 + mt];
  const int n0 = nt << 7;
  __shared__ __align__(16) unsigned short sA[256 * 64], sB[128 * 64];
  const int tid = threadIdx.x, lane = tid & 63, wave = tid >> 6;  // 8 waves
  const int lr = lane >> 3;                 // row-in-instruction 0..7
  const int scol = ((lane & 7) ^ lr) << 3;  // pre-swizzled source chunk (shorts)
  // A: 4 stage-instructions/wave, rows wave*32 + j*8 + lr (gathered via perm)
  const unsigned short* aptr[4];
#pragma unroll
  for (int j = 0; j < 4; j++) {
    int r = row0 + (wave << 5) + (j << 3) + lr;
    if (r > N_TOK - 1) r = N_TOK - 1;
    aptr[j] = xb + (size_t)perm[r] * EMB + scol;
  }
  // B: 2 stage-instructions/wave, rows n0 + wave*16 + j*8 + lr
  const unsigned short* bptr[2];
#pragma unroll
  for (int j = 0; j < 2; j++) {
    int r = n0 + (wave << 4) + (j << 3) + lr;
    bptr[j] = w1t + (size_t)e * EMB * HID + (size_t)r * EMB + scol;
  }
  const int q = lane >> 4, c = lane & 15;
  const int msub = (wave >> 1) << 6;   // 0..192 (4 m-waves)
  const int nsub = (wave & 1) << 6;    // 0,64   (2 n-waves)
  f32x4 acc[4][4];
#pragma unroll
  for (int i = 0; i < 4; i++)
#pragma unroll
    for (int j = 0; j < 4; j++) acc[i][j] = (f32x4){0.f, 0.f, 0.f, 0.f};

#pragma unroll 1
  for (int kk = 0; kk < EMB; kk += 64) {
    async16(aptr[0] + kk, sA + ((wave << 5) + 0)  * 64);
    async16(aptr[1] + kk, sA + ((wave << 5) + 8)  * 64);
    async16(aptr[2] + kk, sA + ((wave << 5) + 16) * 64);
    async16(aptr[3] + kk, sA + ((wave << 5) + 24) * 64);
    async16(bptr[0] + kk, sB + ((wave << 4) + 0)  * 64);
    async16(bptr[1] + kk, sB + ((wave << 4) + 8)  * 64);
    __syncthreads();
#pragma unroll
    for (int ks = 0; ks < 2; ks++) {
      const int coff = ((((ks << 2) + q) ^ (c & 7)) << 3);  // swizzled read col
      s16x8 fa[4], fb[4];
#pragma unroll
      for (int i = 0; i < 4; i++) {
        fa[i] = *(const s16x8*)(sA + ((msub + (i << 4) + c) << 6) + coff);
        fb[i] = *(const s16x8*)(sB + ((nsub + (i << 4) + c) << 6) + coff);
      }
#pragma unroll
      for (int mi = 0; mi < 4; mi++)
#pragma unroll
        for (int ni = 0; ni < 4; ni++)
          acc[mi][ni] = __builtin_amdgcn_mfma_f32_16x16x32_bf16(fa[mi], fb[ni], acc[mi][ni], 0, 0, 0);
    }
    __syncthreads();
  }
#pragma unroll
  for (int mi = 0; mi < 4; mi++)
#pragma unroll
    for (int ni = 0; ni < 4; ni++) {
      int gn = n0 + nsub + (ni << 4) + c;
      float bias = b1[e * HID + gn];
#pragma unroll
      for (int i2 = 0; i2 < 4; i2++) {
        int rs = row0 + msub + (mi << 4) + (q << 2) + i2;
        if (rs < rend) {
          float v = acc[mi][ni][i2] + bias;
          v = v > 0.f ? v : 0.f;
          hidden[(size_t)rs * HID + gn] = f2bf(v);
        }
      }
    }
}

// ---- FFN layer 2: 256x128 tile, BK=64, 8 waves, 48 KB LDS, drain loop ----
// out[perm] = hidden @ W2[e] + b2[e].
// Chunked XCD swizzle (320 = 8*40): each XCD owns 5 m-tiles x 8 n-tiles ->
// A-panel (2 MB) reused 8x from that XCD's L2; r1/r2 measured this exact
// mechanism cutting FETCH 357->119 MB.
__global__ __launch_bounds__(512) void k_ffn2(
    const unsigned short* __restrict__ hidden, const unsigned short* __restrict__ w2t,
    const float* __restrict__ b2, const int* __restrict__ perm,
    const int* __restrict__ meta, float* __restrict__ out) {
  const int wg = (blockIdx.x & 7) * 40 + (blockIdx.x >> 3);  // XCD chunk swizzle
  const int mt = wg >> 3;
  if (mt >= meta[26]) return;
  const int nt = wg & 7;
  const int e = meta[288 + mt];
  const int row0 = meta[368 + mt];
  const int rend = meta[448 + mt];
  const int n0 = nt << 7;
  __shared__ __align__(16) unsigned short sA[256 * 64], sB[128 * 64];
  const int tid = threadIdx.x, lane = tid & 63, wave = tid >> 6;
  const int lr = lane >> 3;
  const int scol = ((lane & 7) ^ lr) << 3;
  const unsigned short* aptr[4];
#pragma unroll
  for (int j = 0; j < 4; j++) {
    int r = row0 + (wave << 5) + (j << 3) + lr;
    if (r > N_TOK - 1) r = N_TOK - 1;      // hidden rows 0..8191 all valid (compact)
    aptr[j] = hidden + (size_t)r * HID + scol;
  }
  const unsigned short* bptr[2];
#pragma unroll
  for (int j = 0; j < 2; j++) {
    int r = n0 + (wave << 4) + (j << 3) + lr;
    bptr[j] = w2t + (size_t)e * HID * EMB + (size_t)r * HID + scol;
  }
  const int q = lane >> 4, c = lane & 15;
  const int msub = (wave >> 1) << 6;
  const int nsub = (wave & 1) << 6;
  f32x4 acc[4][4];
#pragma unroll
  for (int i = 0; i < 4; i++)
#pragma unroll
    for (int j = 0; j < 4; j++) acc[i][j] = (f32x4){0.f, 0.f, 0.f, 0.f};

#pragma unroll 1
  for (int kk = 0; kk < HID; kk += 64) {
    async16(aptr[0] + kk, sA + ((wave << 5) + 0)  * 64);
    async16(aptr[1] + kk, sA + ((wave << 5) + 8)  * 64);
    async16(aptr[2] + kk, sA + ((wave << 5) + 16) * 64);
    async16(aptr[3] + kk, sA + ((wave << 5) + 24) * 64);
    async16(bptr[0] + kk, sB + ((wave << 4) + 0)  * 64);
    async16(bptr[1] + kk, sB + ((wave << 4) + 8)  * 64);
    __syncthreads();
#pragma unroll
    for (int ks = 0; ks < 2; ks++) {
      const int coff = ((((ks << 2) + q) ^ (c & 7)) << 3);
      s16x8 fa[4], fb[4];
#pragma unroll
      for (int i = 0; i < 4; i++) {
        fa[i] = *(const s16x8*)(sA + ((msub + (i << 4) + c) << 6) + coff);
        fb[i] = *(const s16x8*)(sB + ((nsub + (i << 4) + c) << 6) + coff);
      }
#pragma unroll
      for (int mi = 0; mi < 4; mi++)
#pragma unroll
        for (int ni = 0; ni < 4; ni++)
          acc[mi][ni] = __builtin_amdgcn_mfma_f32_16x16x32_bf16(fa[mi], fb[ni], acc[mi][ni], 0, 0, 0);
    }
    __syncthreads();
  }
#pragma unroll
  for (int mi = 0; mi < 4; mi++)
#pragma unroll
    for (int ni = 0; ni < 4; ni++) {
      int gn = n0 + nsub + (ni << 4) + c;
      float bias = b2[e * EMB + gn];
#pragma unroll
      for (int i2 = 0; i2 < 4; i2++) {
        int rs = row0 + msub + (mi << 4) + (q << 2) + i2;
        if (rs < rend) {
          int orig = perm[rs];
          out[(size_t)orig * EMB + gn] = acc[mi][ni][i2] + bias;
        }
      }
    }
}

// ---- launch ----
// Workspace layout (bytes). REQUIRES ws_size >= 289,476,608 (~276 MiB).
extern "C" void kernel_launch(void* const* d_in, const int* in_sizes, int n_in,
                              void* d_out, int out_size, void* d_ws, size_t ws_size,
                              hipStream_t stream) {
  const float* x   = (const float*)d_in[0];
  const float* Wr1 = (const float*)d_in[1];
  const float* br1 = (const float*)d_in[2];
  const float* Wr2 = (const float*)d_in[3];
  const float* br2 = (const float*)d_in[4];
  const float* W1  = (const float*)d_in[5];
  const float* b1  = (const float*)d_in[6];
  const float* W2  = (const float*)d_in[7];
  const float* b2  = (const float*)d_in[8];
  float* out = (float*)d_out;
  char* ws = (char*)d_ws;

  unsigned short* w1t    = (unsigned short*)(ws + 0);          // 67,108,864
  unsigned short* w2t    = (unsigned short*)(ws + 67108864);   // 67,108,864
  unsigned short* xb     = (unsigned short*)(ws + 134217728);  // 16,777,216
  _Float16*       xhi    = (_Float16*)(ws + 150994944);        // 16,777,216
  _Float16*       xlo    = (_Float16*)(ws + 167772160);        // 16,777,216
  _Float16*       whi    = (_Float16*)(ws + 184549376);        //  2,097,152
  _Float16*       wlo    = (_Float16*)(ws + 186646528);        //  2,097,152
  float*          hbuf   = (float*)(ws + 188743680);           // 33,554,432
  unsigned short* hidden = (unsigned short*)(ws + 222298112);  // 67,108,864
  int*            chosen = (int*)(ws + 289406976);             //     32,768
  int*            perm   = (int*)(ws + 289439744);             //     32,768
  int*            meta   = (int*)(ws + 289472512);             //      4,096

  k_cast_x<<<dim3(8192), dim3(256), 0, stream>>>(x, xb, xhi, xlo);
  k_trans_wr1<<<dim3(64), dim3(256), 0, stream>>>(Wr1, whi, wlo);
  // W1: K=1024 (EMB), Nn=4096 (HID): ktiles=16, ntiles=16 -> 8*256=2048 blocks
  k_transcast_v2<<<dim3(2048), dim3(256), 0, stream>>>(W1, w1t, 1024, 4096, 16, 16);
  // W2: K=4096 (HID), Nn=1024 (EMB): ktiles=64, ntiles=4 -> 8*256=2048 blocks
  k_transcast_v2<<<dim3(2048), dim3(256), 0, stream>>>(W2, w2t, 4096, 1024, 64, 4);
  k_router_gemm<<<dim3(512), dim3(256), 0, stream>>>(xhi, xlo, whi, wlo, br1, hbuf);
  k_logits<<<dim3(2048), dim3(256), 0, stream>>>(hbuf, Wr2, br2, chosen);
  k_zero<<<dim3(1), dim3(256), 0, stream>>>(meta);
  k_hist<<<dim3(32), dim3(256), 0, stream>>>(chosen, meta);
  k_sched<<<dim3(1), dim3(128), 0, stream>>>(meta);
  k_scatter<<<dim3(32), dim3(256), 0, stream>>>(chosen, meta, perm);
  // 256-row tiles: T2 <= 40 -> grids 40*32 and 40*8
  k_ffn1<<<dim3(1280), dim3(512), 0, stream>>>(xb, w1t, b1, perm, meta, hidden);
  k_ffn2<<<dim3(320), dim3(512), 0, stream>>>(hidden, w2t, b2, perm, meta, out);
}

// Round 6
// 695.478 us; speedup vs baseline: 1.1181x; 1.1181x over previous
//
#include <hip/hip_runtime.h>
#include <stdint.h>

#define N_TOK 8192
#define EMB 1024
#define HID 4096
#define NEXP 8

// ---- types ----
typedef _Float16 f16x8 __attribute__((ext_vector_type(8)));
typedef _Float16 f16x4 __attribute__((ext_vector_type(4)));
typedef short    s16x8 __attribute__((ext_vector_type(8)));
typedef unsigned short u16x8 __attribute__((ext_vector_type(8)));
typedef float    f32x4 __attribute__((ext_vector_type(4)));

typedef __attribute__((address_space(1))) const void gvoid_t;
typedef __attribute__((address_space(3))) void lvoid_t;

__device__ __forceinline__ void async16(const void* g, void* l) {
  __builtin_amdgcn_global_load_lds((gvoid_t*)g, (lvoid_t*)l, 16, 0, 0);
}

__device__ __forceinline__ unsigned short f2bf(float f) {
  unsigned u = __builtin_bit_cast(unsigned, f);
  u += 0x7fffu + ((u >> 16) & 1u);   // RTNE (no NaN in this data)
  return (unsigned short)(u >> 16);
}

// ---- cast x -> bf16 (FFN A operand) + fp16 hi/lo split (router A operand) ----
__global__ __launch_bounds__(256) void k_cast_x(const float* __restrict__ x,
    unsigned short* __restrict__ xb, _Float16* __restrict__ xhi, _Float16* __restrict__ xlo) {
  int i = (blockIdx.x * 256 + threadIdx.x) << 2;
  float4 v = *(const float4*)(x + i);
  ushort4 b;
  b.x = f2bf(v.x); b.y = f2bf(v.y); b.z = f2bf(v.z); b.w = f2bf(v.w);
  *(ushort4*)(xb + i) = b;
  float vv[4] = {v.x, v.y, v.z, v.w};
  f16x4 hi, lo;
#pragma unroll
  for (int j = 0; j < 4; j++) {
    _Float16 h = (_Float16)vv[j];
    hi[j] = h;
    lo[j] = (_Float16)(vv[j] - (float)h);
  }
  *(f16x4*)(xhi + i) = hi;
  *(f16x4*)(xlo + i) = lo;
}

// ---- transpose+cast Wr1 [k][n] -> [n][k] fp16 hi/lo, scaled by 256 (argmax-invariant) ----
__global__ __launch_bounds__(256) void k_trans_wr1(const float* __restrict__ src,
    _Float16* __restrict__ dhi, _Float16* __restrict__ dlo) {
  int nblk = blockIdx.x >> 4, kc = blockIdx.x & 15;
  int n = (nblk << 8) + threadIdx.x;
  int k0 = kc << 6;
  for (int k = k0; k < k0 + 64; k += 8) {
    f16x8 hi, lo;
#pragma unroll
    for (int j = 0; j < 8; j++) {
      float w = src[(size_t)(k + j) * EMB + n] * 256.0f;
      _Float16 h = (_Float16)w;
      hi[j] = h;
      lo[j] = (_Float16)(w - (float)h);
    }
    *(f16x8*)(dhi + (size_t)n * EMB + k) = hi;
    *(f16x8*)(dlo + (size_t)n * EMB + k) = lo;
  }
}

// ---- LDS-tiled transpose+cast expert weights [e][K][Nn] fp32 -> [e][Nn][K] bf16 ----
__global__ __launch_bounds__(256) void k_transcast_v2(const float* __restrict__ src,
    unsigned short* __restrict__ dst, int K, int Nn, int ktiles, int ntiles) {
  __shared__ __align__(16) unsigned short lds[256 * 72];  // 36,864 B, row stride 72
  int b = blockIdx.x;
  int e = b / (ktiles * ntiles);
  int r = b % (ktiles * ntiles);
  int kt = r / ntiles, nt = r % ntiles;
  int k0 = kt << 6, n0 = nt << 8;
  const float* s = src + (size_t)e * K * Nn;
  unsigned short* d = dst + (size_t)e * K * Nn;
  int tid = threadIdx.x;
  const float* scol = s + n0 + tid;
#pragma unroll 4
  for (int k = 0; k < 64; k += 2) {
    float a  = scol[(size_t)(k0 + k) * Nn];
    float bv = scol[(size_t)(k0 + k + 1) * Nn];
    unsigned p = (unsigned)f2bf(a) | ((unsigned)f2bf(bv) << 16);
    *(unsigned*)(lds + tid * 72 + k) = p;
  }
  __syncthreads();
  int c = tid & 7, nl = tid >> 3;
#pragma unroll
  for (int p2 = 0; p2 < 8; p2++) {
    int n = (p2 << 5) + nl;
    u16x8 v = *(const u16x8*)(lds + n * 72 + (c << 3));
    *(u16x8*)(d + (size_t)(n0 + n) * K + k0 + (c << 3)) = v;
  }
}

// ---- router GEMM: h_s = relu(256*(x@Wr1+br1)) via fp16 2-way split, fp32-accurate ----
// (exact round-0 structure: best measured)
__global__ __launch_bounds__(256) void k_router_gemm(
    const _Float16* __restrict__ Ah, const _Float16* __restrict__ Al,
    const _Float16* __restrict__ Bh, const _Float16* __restrict__ Bl,
    const float* __restrict__ br1, float* __restrict__ hOut) {
  __shared__ __align__(16) _Float16 sAh[4096], sAl[4096], sBh[4096], sBl[4096];
  const int tid = threadIdx.x, lane = tid & 63, wave = tid >> 6;
  const int m0 = (blockIdx.x >> 3) << 7;
  const int n0 = (blockIdx.x & 7) << 7;
  const int srow = (wave << 5) + (lane >> 2);
  const int scol = (lane & 3) << 3;
  const size_t aBase = (size_t)(m0 + srow) * EMB + scol;
  const size_t bBase = (size_t)(n0 + srow) * EMB + scol;
  _Float16* lAh = sAh + (wave << 10);
  _Float16* lAl = sAl + (wave << 10);
  _Float16* lBh = sBh + (wave << 10);
  _Float16* lBl = sBl + (wave << 10);
  const int q = lane >> 4, c = lane & 15;
  const int msub = (wave & 1) << 6, nsub = (wave >> 1) << 6;
  f32x4 acc[4][4];
#pragma unroll
  for (int i = 0; i < 4; i++)
#pragma unroll
    for (int j = 0; j < 4; j++) acc[i][j] = (f32x4){0.f, 0.f, 0.f, 0.f};

  for (int kk = 0; kk < EMB; kk += 32) {
    async16(Ah + aBase + kk, lAh);
    async16(Ah + aBase + 16 * EMB + kk, lAh + 512);
    async16(Al + aBase + kk, lAl);
    async16(Al + aBase + 16 * EMB + kk, lAl + 512);
    async16(Bh + bBase + kk, lBh);
    async16(Bh + bBase + 16 * EMB + kk, lBh + 512);
    async16(Bl + bBase + kk, lBl);
    async16(Bl + bBase + 16 * EMB + kk, lBl + 512);
    __syncthreads();
    f16x8 fah[4], fal[4], fbh[4], fbl[4];
#pragma unroll
    for (int i = 0; i < 4; i++) {
      int ar = msub + (i << 4) + c;
      int br = nsub + (i << 4) + c;
      fah[i] = *(const f16x8*)(sAh + (ar << 5) + (q << 3));
      fal[i] = *(const f16x8*)(sAl + (ar << 5) + (q << 3));
      fbh[i] = *(const f16x8*)(sBh + (br << 5) + (q << 3));
      fbl[i] = *(const f16x8*)(sBl + (br << 5) + (q << 3));
    }
#pragma unroll
    for (int mi = 0; mi < 4; mi++)
#pragma unroll
      for (int ni = 0; ni < 4; ni++) {
        acc[mi][ni] = __builtin_amdgcn_mfma_f32_16x16x32_f16(fah[mi], fbh[ni], acc[mi][ni], 0, 0, 0);
        acc[mi][ni] = __builtin_amdgcn_mfma_f32_16x16x32_f16(fah[mi], fbl[ni], acc[mi][ni], 0, 0, 0);
        acc[mi][ni] = __builtin_amdgcn_mfma_f32_16x16x32_f16(fal[mi], fbh[ni], acc[mi][ni], 0, 0, 0);
      }
    __syncthreads();
  }
#pragma unroll
  for (int mi = 0; mi < 4; mi++)
#pragma unroll
    for (int ni = 0; ni < 4; ni++) {
      int gn = n0 + nsub + (ni << 4) + c;
      float bias = 256.0f * br1[gn];
#pragma unroll
      for (int i2 = 0; i2 < 4; i2++) {
        int gm = m0 + msub + (mi << 4) + (q << 2) + i2;
        float v = acc[mi][ni][i2] + bias;
        hOut[(size_t)gm * EMB + gn] = v > 0.f ? v : 0.f;
      }
    }
}

// ---- logits + argmax (first-max tie-break, matches np.argmax) ----
__global__ __launch_bounds__(256) void k_logits(const float* __restrict__ h,
    const float* __restrict__ Wr2, const float* __restrict__ br2, int* __restrict__ chosen) {
  __shared__ __align__(16) float sW[EMB * NEXP];
  int tid = threadIdx.x;
  for (int i = tid; i < EMB * NEXP; i += 256) sW[i] = Wr2[i];
  __syncthreads();
  int lane = tid & 63, wave = tid >> 6;
  int t = blockIdx.x * 4 + wave;
  const float* hr = h + (size_t)t * EMB;
  float acc[8] = {0.f, 0.f, 0.f, 0.f, 0.f, 0.f, 0.f, 0.f};
#pragma unroll
  for (int i = 0; i < 16; i++) {
    int k = (i << 6) + lane;
    float v = hr[k];
    float4 w0 = *(const float4*)(sW + (k << 3));
    float4 w1 = *(const float4*)(sW + (k << 3) + 4);
    acc[0] += v * w0.x; acc[1] += v * w0.y; acc[2] += v * w0.z; acc[3] += v * w0.w;
    acc[4] += v * w1.x; acc[5] += v * w1.y; acc[6] += v * w1.z; acc[7] += v * w1.w;
  }
#pragma unroll
  for (int off = 32; off > 0; off >>= 1)
#pragma unroll
    for (int e = 0; e < 8; e++) acc[e] += __shfl_down(acc[e], off);
  if (lane == 0) {
    float best = acc[0] + 256.0f * br2[0];
    int bi = 0;
#pragma unroll
    for (int e = 1; e < 8; e++) {
      float l = acc[e] + 256.0f * br2[e];
      if (l > best) { best = l; bi = e; }
    }
    chosen[t] = bi;
  }
}

// ---- fused routing bookkeeping: hist + prefix + 256-row schedule + scatter ----
// Single block, 256 threads. Replaces k_zero/k_hist/k_sched/k_scatter (3 fewer
// launch gaps). Within-expert perm order is nondeterministic (atomic cursors),
// same semantics as before.
// meta: [16..23] offsets, [26] T256, [288..] e, [368..] m0, [448..] end
__global__ __launch_bounds__(256) void k_route(const int* __restrict__ chosen,
                                               int* meta, int* __restrict__ perm) {
  __shared__ int cnt[8], cur[8];
  int tid = threadIdx.x;
  if (tid < 8) { cnt[tid] = 0; cur[tid] = 0; }
  __syncthreads();
  for (int i = tid; i < N_TOK; i += 256) atomicAdd(&cnt[chosen[i]], 1);
  __syncthreads();
  int off[9]; off[0] = 0;
#pragma unroll
  for (int e = 0; e < 8; e++) off[e + 1] = off[e] + cnt[e];
  if (tid < 8) meta[16 + tid] = off[tid];
  int ts2[9]; ts2[0] = 0;
#pragma unroll
  for (int e = 0; e < 8; e++) ts2[e + 1] = ts2[e] + ((cnt[e] + 255) >> 8);
  int T2 = ts2[8];
  if (tid == 0) meta[26] = T2;
  if (tid < T2) {
    int e = 0;
    while (ts2[e + 1] <= tid) e++;
    int m = off[e] + ((tid - ts2[e]) << 8);
    int end = off[e + 1];
    meta[288 + tid] = e;
    meta[368 + tid] = m;
    meta[448 + tid] = (m + 256 < end) ? m + 256 : end;
  }
  // scatter (uses local off[] + LDS cursors; no extra barrier needed)
  for (int i = tid; i < N_TOK; i += 256) {
    int e = chosen[i];
    int pos = off[e] + atomicAdd(&cur[e], 1);
    perm[pos] = i;
  }
}

// ---- FFN layer 1: 256x128 tile, BK=64, 8 waves, 48 KB LDS, drain loop ----
// hidden = relu(x[perm] @ W1[e] + b1[e]).
// Chunked XCD swizzle (1280 = 8*160): A-panel reused from each XCD's L2.
__global__ __launch_bounds__(512) void k_ffn1(
    const unsigned short* __restrict__ xb, const unsigned short* __restrict__ w1t,
    const float* __restrict__ b1, const int* __restrict__ perm,
    const int* __restrict__ meta, unsigned short* __restrict__ hidden) {
  const int wg = (blockIdx.x & 7) * 160 + (blockIdx.x >> 3);  // XCD chunk swizzle
  const int mt = wg >> 5;
  if (mt >= meta[26]) return;
  const int nt = wg & 31;
  const int e = meta[288 + mt];
  const int row0 = meta[368 + mt];
  const int rend = meta[448 + mt];
  const int n0 = nt << 7;
  __shared__ __align__(16) unsigned short sA[256 * 64], sB[128 * 64];
  const int tid = threadIdx.x, lane = tid & 63, wave = tid >> 6;  // 8 waves
  const int lr = lane >> 3;                 // row-in-instruction 0..7
  const int scol = ((lane & 7) ^ lr) << 3;  // pre-swizzled source chunk (shorts)
  const unsigned short* aptr[4];
#pragma unroll
  for (int j = 0; j < 4; j++) {
    int r = row0 + (wave << 5) + (j << 3) + lr;
    if (r > N_TOK - 1) r = N_TOK - 1;
    aptr[j] = xb + (size_t)perm[r] * EMB + scol;
  }
  const unsigned short* bptr[2];
#pragma unroll
  for (int j = 0; j < 2; j++) {
    int r = n0 + (wave << 4) + (j << 3) + lr;
    bptr[j] = w1t + (size_t)e * EMB * HID + (size_t)r * EMB + scol;
  }
  const int q = lane >> 4, c = lane & 15;
  const int msub = (wave >> 1) << 6;   // 0..192 (4 m-waves)
  const int nsub = (wave & 1) << 6;    // 0,64   (2 n-waves)
  f32x4 acc[4][4];
#pragma unroll
  for (int i = 0; i < 4; i++)
#pragma unroll
    for (int j = 0; j < 4; j++) acc[i][j] = (f32x4){0.f, 0.f, 0.f, 0.f};

#pragma unroll 1
  for (int kk = 0; kk < EMB; kk += 64) {
    async16(aptr[0] + kk, sA + ((wave << 5) + 0)  * 64);
    async16(aptr[1] + kk, sA + ((wave << 5) + 8)  * 64);
    async16(aptr[2] + kk, sA + ((wave << 5) + 16) * 64);
    async16(aptr[3] + kk, sA + ((wave << 5) + 24) * 64);
    async16(bptr[0] + kk, sB + ((wave << 4) + 0)  * 64);
    async16(bptr[1] + kk, sB + ((wave << 4) + 8)  * 64);
    __syncthreads();
#pragma unroll
    for (int ks = 0; ks < 2; ks++) {
      const int coff = ((((ks << 2) + q) ^ (c & 7)) << 3);  // swizzled read col
      s16x8 fa[4], fb[4];
#pragma unroll
      for (int i = 0; i < 4; i++) {
        fa[i] = *(const s16x8*)(sA + ((msub + (i << 4) + c) << 6) + coff);
        fb[i] = *(const s16x8*)(sB + ((nsub + (i << 4) + c) << 6) + coff);
      }
#pragma unroll
      for (int mi = 0; mi < 4; mi++)
#pragma unroll
        for (int ni = 0; ni < 4; ni++)
          acc[mi][ni] = __builtin_amdgcn_mfma_f32_16x16x32_bf16(fa[mi], fb[ni], acc[mi][ni], 0, 0, 0);
    }
    __syncthreads();
  }
#pragma unroll
  for (int mi = 0; mi < 4; mi++)
#pragma unroll
    for (int ni = 0; ni < 4; ni++) {
      int gn = n0 + nsub + (ni << 4) + c;
      float bias = b1[e * HID + gn];
#pragma unroll
      for (int i2 = 0; i2 < 4; i2++) {
        int rs = row0 + msub + (mi << 4) + (q << 2) + i2;
        if (rs < rend) {
          float v = acc[mi][ni][i2] + bias;
          v = v > 0.f ? v : 0.f;
          hidden[(size_t)rs * HID + gn] = f2bf(v);
        }
      }
    }
}

// ---- FFN layer 2: SPLIT-K=2 x 256x128 tile, BK=64, 8 waves, 48 KB LDS ----
// p[kc][rs][gn] = hidden[rs][kc*2048:+2048] @ W2[e][...,n].  Grid 640 = 2*40*8
// -> 2.5 blocks/CU supply, 3 resident (48KB LDS) -> drain of one block hides
// under MFMA of a co-resident one (m114 wave-level overlap).
// wg = kc*320 + mt*8 + nt, chunked XCD swizzle (640 = 8*80): each XCD span has
// one kc and contiguous mt -> A/B panels L2-resident (r5: FETCH 87MB minimal).
__global__ __launch_bounds__(512) void k_ffn2(
    const unsigned short* __restrict__ hidden, const unsigned short* __restrict__ w2t,
    const int* __restrict__ meta, float* __restrict__ p0, float* __restrict__ p1) {
  const int wg = (blockIdx.x & 7) * 80 + (blockIdx.x >> 3);  // XCD chunk swizzle
  const int kc = wg / 320;
  const int r  = wg % 320;
  const int mt = r >> 3;
  if (mt >= meta[26]) return;
  const int nt = r & 7;
  const int e = meta[288 + mt];
  const int row0 = meta[368 + mt];
  const int rend = meta[448 + mt];
  const int n0 = nt << 7;
  const int kbase = kc << 11;              // 0 or 2048
  __shared__ __align__(16) unsigned short sA[256 * 64], sB[128 * 64];
  const int tid = threadIdx.x, lane = tid & 63, wave = tid >> 6;
  const int lr = lane >> 3;
  const int scol = ((lane & 7) ^ lr) << 3;
  const unsigned short* aptr[4];
#pragma unroll
  for (int j = 0; j < 4; j++) {
    int rr = row0 + (wave << 5) + (j << 3) + lr;
    if (rr > N_TOK - 1) rr = N_TOK - 1;    // hidden rows 0..8191 all valid (compact)
    aptr[j] = hidden + (size_t)rr * HID + kbase + scol;
  }
  const unsigned short* bptr[2];
#pragma unroll
  for (int j = 0; j < 2; j++) {
    int rr = n0 + (wave << 4) + (j << 3) + lr;
    bptr[j] = w2t + (size_t)e * HID * EMB + (size_t)rr * HID + kbase + scol;
  }
  const int q = lane >> 4, c = lane & 15;
  const int msub = (wave >> 1) << 6;
  const int nsub = (wave & 1) << 6;
  f32x4 acc[4][4];
#pragma unroll
  for (int i = 0; i < 4; i++)
#pragma unroll
    for (int j = 0; j < 4; j++) acc[i][j] = (f32x4){0.f, 0.f, 0.f, 0.f};

#pragma unroll 1
  for (int kk = 0; kk < 2048; kk += 64) {
    async16(aptr[0] + kk, sA + ((wave << 5) + 0)  * 64);
    async16(aptr[1] + kk, sA + ((wave << 5) + 8)  * 64);
    async16(aptr[2] + kk, sA + ((wave << 5) + 16) * 64);
    async16(aptr[3] + kk, sA + ((wave << 5) + 24) * 64);
    async16(bptr[0] + kk, sB + ((wave << 4) + 0)  * 64);
    async16(bptr[1] + kk, sB + ((wave << 4) + 8)  * 64);
    __syncthreads();
#pragma unroll
    for (int ks = 0; ks < 2; ks++) {
      const int coff = ((((ks << 2) + q) ^ (c & 7)) << 3);
      s16x8 fa[4], fb[4];
#pragma unroll
      for (int i = 0; i < 4; i++) {
        fa[i] = *(const s16x8*)(sA + ((msub + (i << 4) + c) << 6) + coff);
        fb[i] = *(const s16x8*)(sB + ((nsub + (i << 4) + c) << 6) + coff);
      }
#pragma unroll
      for (int mi = 0; mi < 4; mi++)
#pragma unroll
        for (int ni = 0; ni < 4; ni++)
          acc[mi][ni] = __builtin_amdgcn_mfma_f32_16x16x32_bf16(fa[mi], fb[ni], acc[mi][ni], 0, 0, 0);
    }
    __syncthreads();
  }
  float* pout = kc ? p1 : p0;
#pragma unroll
  for (int mi = 0; mi < 4; mi++)
#pragma unroll
    for (int ni = 0; ni < 4; ni++) {
      int gn = n0 + nsub + (ni << 4) + c;
#pragma unroll
      for (int i2 = 0; i2 < 4; i2++) {
        int rs = row0 + msub + (mi << 4) + (q << 2) + i2;
        if (rs < rend) pout[((size_t)rs << 10) + gn] = acc[mi][ni][i2];
      }
    }
}

// ---- split-K reduce + bias + perm-scatter: out[perm[rs]] = p0+p1 + b2[e] ----
__global__ __launch_bounds__(256) void k_reduce(
    const float* __restrict__ p0, const float* __restrict__ p1,
    const float* __restrict__ b2, const int* __restrict__ perm,
    const int* __restrict__ chosen, float* __restrict__ out) {
  int rs = blockIdx.x;
  int n = threadIdx.x << 2;
  int orig = perm[rs];
  int e = chosen[orig];
  size_t idx = ((size_t)rs << 10) + n;
  float4 a = *(const float4*)(p0 + idx);
  float4 b = *(const float4*)(p1 + idx);
  float4 bb = *(const float4*)(b2 + e * EMB + n);
  float4 rv;
  rv.x = a.x + b.x + bb.x;
  rv.y = a.y + b.y + bb.y;
  rv.z = a.z + b.z + bb.z;
  rv.w = a.w + b.w + bb.w;
  *(float4*)(out + ((size_t)orig << 10) + n) = rv;
}

// ---- launch ----
// Workspace layout (bytes). REQUIRES ws_size >= 289,476,608 (~276 MiB).
// Split-K partials alias w1t (dead after k_ffn1): p0 = ws+0, p1 = ws+32M.
extern "C" void kernel_launch(void* const* d_in, const int* in_sizes, int n_in,
                              void* d_out, int out_size, void* d_ws, size_t ws_size,
                              hipStream_t stream) {
  const float* x   = (const float*)d_in[0];
  const float* Wr1 = (const float*)d_in[1];
  const float* br1 = (const float*)d_in[2];
  const float* Wr2 = (const float*)d_in[3];
  const float* br2 = (const float*)d_in[4];
  const float* W1  = (const float*)d_in[5];
  const float* b1  = (const float*)d_in[6];
  const float* W2  = (const float*)d_in[7];
  const float* b2  = (const float*)d_in[8];
  float* out = (float*)d_out;
  char* ws = (char*)d_ws;

  unsigned short* w1t    = (unsigned short*)(ws + 0);          // 67,108,864
  unsigned short* w2t    = (unsigned short*)(ws + 67108864);   // 67,108,864
  unsigned short* xb     = (unsigned short*)(ws + 134217728);  // 16,777,216
  _Float16*       xhi    = (_Float16*)(ws + 150994944);        // 16,777,216
  _Float16*       xlo    = (_Float16*)(ws + 167772160);        // 16,777,216
  _Float16*       whi    = (_Float16*)(ws + 184549376);        //  2,097,152
  _Float16*       wlo    = (_Float16*)(ws + 186646528);        //  2,097,152
  float*          hbuf   = (float*)(ws + 188743680);           // 33,554,432
  unsigned short* hidden = (unsigned short*)(ws + 222298112);  // 67,108,864
  int*            chosen = (int*)(ws + 289406976);             //     32,768
  int*            perm   = (int*)(ws + 289439744);             //     32,768
  int*            meta   = (int*)(ws + 289472512);             //      4,096
  float*          p0     = (float*)(ws + 0);                   // 33,554,432 (aliases w1t)
  float*          p1     = (float*)(ws + 33554432);            // 33,554,432 (aliases w1t)

  k_cast_x<<<dim3(8192), dim3(256), 0, stream>>>(x, xb, xhi, xlo);
  k_trans_wr1<<<dim3(64), dim3(256), 0, stream>>>(Wr1, whi, wlo);
  // W1: K=1024 (EMB), Nn=4096 (HID): ktiles=16, ntiles=16 -> 8*256=2048 blocks
  k_transcast_v2<<<dim3(2048), dim3(256), 0, stream>>>(W1, w1t, 1024, 4096, 16, 16);
  // W2: K=4096 (HID), Nn=1024 (EMB): ktiles=64, ntiles=4 -> 8*256=2048 blocks
  k_transcast_v2<<<dim3(2048), dim3(256), 0, stream>>>(W2, w2t, 4096, 1024, 64, 4);
  k_router_gemm<<<dim3(512), dim3(256), 0, stream>>>(xhi, xlo, whi, wlo, br1, hbuf);
  k_logits<<<dim3(2048), dim3(256), 0, stream>>>(hbuf, Wr2, br2, chosen);
  k_route<<<dim3(1), dim3(256), 0, stream>>>(chosen, meta, perm);
  // 256-row tiles: T2 <= 40
  k_ffn1<<<dim3(1280), dim3(512), 0, stream>>>(xb, w1t, b1, perm, meta, hidden);
  k_ffn2<<<dim3(640), dim3(512), 0, stream>>>(hidden, w2t, meta, p0, p1);
  k_reduce<<<dim3(8192), dim3(256), 0, stream>>>(p0, p1, b2, perm, chosen, out);
}